// Round 5
// baseline (189.364 us; speedup 1.0000x reference)
//
#include <hip/hip_runtime.h>
#include <hip/hip_fp16.h>

// CapsuleLayer dynamic routing — round 5: de-serialize the routing loop.
//  * butterfly reduction hoisted out of the bi loop (register-banked s_acc[4][8],
//    reduce once per 4 batch elements instead of every bi)
//  * softmax Z via concurrent LDS float atomics from all 10 waves (no
//    single-wave serialization), triple-buffered so only ONE barrier per bi
//  * round 0: c = softmax(bias) hoisted -> zero barriers / zero DS in its loop
//  * squash fused into the consuming round kernel (v precomputed into LDS)
//  * BT=8 batch reuse of the register-resident W fragment

#define IC 1152
#define IE 8
#define NC 10
#define DV 16
#define NB 256
#define NW (IC * NC * IE * DV)  // 1,474,560
#define NGP (IC / 32)           // 36 row-groups of 32
#define BT 8                    // batch elements per block
#define NBG (NB / BT)           // 32
#define TPB 640                 // wave w <-> output capsule j=w
#define SOUT (NC * DV)          // 160
#define SB (NB * SOUT)          // 40,960 floats per s buffer

typedef _Float16 h2 __attribute__((ext_vector_type(2)));
union WChunk { int4 v; h2 p[4]; _Float16 h[8]; };

static __device__ inline float fdot2f(h2 a, h2 b, float c) {
#if defined(__has_builtin) && __has_builtin(__builtin_amdgcn_fdot2)
    return __builtin_amdgcn_fdot2(a, b, c, false);
#else
    return fmaf((float)a.x, (float)b.x, fmaf((float)a.y, (float)b.y, c));
#endif
}

// W fp32 [i][j][e][d] -> fp16 chunks Wc[((Gp*10+j)*8+k)*64 + lane], where
// lane = h*32+r, i = Gp*32+r, d = h*8+k; chunk holds e=0..7 halves of W[i,j,:,d].
__global__ void wprep_kernel(const float* __restrict__ W, int4* __restrict__ Wc) {
    const int t = blockIdx.x * blockDim.x + threadIdx.x;
    if (t >= NW / 8) return;
    const int lane = t & 63;
    const int h = lane >> 5, r = lane & 31;
    const int k = (t >> 6) & 7;
    const int r2 = t >> 9;  // Gp*10 + j
    const int j = r2 % NC, Gp = r2 / NC;
    const int i = Gp * 32 + r;
    const int d = h * 8 + k;
    const float* src = W + ((size_t)(i * NC + j) * IE) * DV + d;  // e-stride DV
    WChunk c;
#pragma unroll
    for (int e = 0; e < IE; ++e) c.h[e] = (_Float16)src[(size_t)e * DV];
    Wc[t] = c.v;
}

__global__ void zero_kernel(float4* __restrict__ p) {
    p[blockIdx.x * blockDim.x + threadIdx.x] = make_float4(0.f, 0.f, 0.f, 0.f);
}

template <int R>
__global__ __launch_bounds__(TPB, 5) void round_kernel(
    const float* __restrict__ X,     // [B, IC, IE] fp32
    const int4* __restrict__ Wc,     // coalesced fp16 layout (see wprep)
    const float* __restrict__ bias,  // [IC*NC] fp32
    const float* __restrict__ sA,    // s from prev round (R>=1)
    const float* __restrict__ sBv,   // s from round 1 (R==2)
    float* __restrict__ s_out)       // [B*160] accumulated via atomics
{
    __shared__ float vA[BT * SOUT];  // fused-squash v (R1) / v1+v2 (R2)
    __shared__ float Zb[3][32];      // triple-buffered per-row sum(exp)
    __shared__ float Z0[32];         // round-0 Z

    const int Gp = blockIdx.x;   // 0..35
    const int bg = blockIdx.y;   // 0..31
    const int tid = threadIdx.x;
    const int j = tid >> 6;      // wave = output capsule
    const int g = tid & 63;
    const int h = g >> 5;        // d-half: d = h*8 + k
    const int r = g & 31;        // row within group
    const int i = Gp * 32 + r;

    // W fragment: 8 int4 (32 VGPRs), lane-consecutive => coalesced
    WChunk w[8];
    {
        const int4* wp = Wc + ((size_t)(Gp * NC + j) * 8) * 64 + g;
#pragma unroll
        for (int k = 0; k < 8; ++k) w[k].v = wp[k * 64];
    }
    const float lt_bias = bias[i * NC + j];

    if (tid < 96) ((float*)Zb)[tid] = 0.f;
    if (R == 0 && tid < 32) Z0[tid] = 0.f;

    if (R >= 1) {
        // fused squash: v (and vsum for R2) into LDS, one thread per (bi,j,h)
        if (tid < BT * 20) {
            const int bi = tid / 20, rem = tid - bi * 20;
            const int jj = rem >> 1, hh = rem & 1;
            const int b = bg * BT + bi;
            const float4* sp = (const float4*)(sA + (size_t)b * SOUT + jj * DV + hh * 8);
            float4 a0 = sp[0], a1 = sp[1];
            float s8[8] = {a0.x, a0.y, a0.z, a0.w, a1.x, a1.y, a1.z, a1.w};
            float sq = 0.f;
#pragma unroll
            for (int k = 0; k < 8; ++k) sq = fmaf(s8[k], s8[k], sq);
            float sqf = sq + __shfl_xor(sq, 1);
            float sc = sqrtf(sqf) / (1.f + sqf);
            float v8[8];
#pragma unroll
            for (int k = 0; k < 8; ++k) v8[k] = sc * s8[k];
            if (R == 2) {
                const float4* tp = (const float4*)(sBv + (size_t)b * SOUT + jj * DV + hh * 8);
                float4 b0 = tp[0], b1 = tp[1];
                float t8[8] = {b0.x, b0.y, b0.z, b0.w, b1.x, b1.y, b1.z, b1.w};
                float tq = 0.f;
#pragma unroll
                for (int k = 0; k < 8; ++k) tq = fmaf(t8[k], t8[k], tq);
                float tqf = tq + __shfl_xor(tq, 1);
                float tsc = sqrtf(tqf) / (1.f + tqf);
#pragma unroll
                for (int k = 0; k < 8; ++k) v8[k] = fmaf(tsc, t8[k], v8[k]);
            }
#pragma unroll
            for (int k = 0; k < 8; ++k) vA[bi * SOUT + jj * DV + hh * 8 + k] = v8[k];
        }
        __syncthreads();  // vA ready; Zb[0] zeroed
    }

    float c0 = 0.f;
    if (R == 0) {
        __syncthreads();  // Z0 zeroed
        float ex0 = __expf(lt_bias);
        if (h == 0) atomicAdd(&Z0[r], ex0);
        __syncthreads();
        c0 = ex0 * __builtin_amdgcn_rcpf(Z0[r]);
    }

    float s_acc[32];
#pragma unroll
    for (int k = 0; k < 32; ++k) s_acc[k] = 0.f;

    for (int bi = 0; bi < BT; ++bi) {
        const int b = bg * BT + bi;

        const float4* xr = (const float4*)(X + ((size_t)b * IC + i) * IE);
        float4 x0 = xr[0], x1 = xr[1];
        h2 x2[4];
        x2[0] = h2{(_Float16)x0.x, (_Float16)x0.y};
        x2[1] = h2{(_Float16)x0.z, (_Float16)x0.w};
        x2[2] = h2{(_Float16)x1.x, (_Float16)x1.y};
        x2[3] = h2{(_Float16)x1.z, (_Float16)x1.w};

        float hat[8];
#pragma unroll
        for (int k = 0; k < 8; ++k) {
            float a = 0.f;
#pragma unroll
            for (int q = 0; q < 4; ++q) a = fdot2f(x2[q], w[k].p[q], a);
            hat[k] = a;
        }

        float c;
        if (R >= 1) {
            const float4* vp = (const float4*)&vA[bi * SOUT + j * DV + h * 8];
            float4 va = vp[0], vb = vp[1];
            const float vv[8] = {va.x, va.y, va.z, va.w, vb.x, vb.y, vb.z, vb.w};
            float ah = 0.f;
#pragma unroll
            for (int k = 0; k < 8; ++k) ah = fmaf(hat[k], vv[k], ah);
            const float lt = lt_bias + ah + __shfl_xor(ah, 32);
            const float ex = __expf(lt);
            if (h == 0) atomicAdd(&Zb[bi % 3][r], ex);  // 10 waves concurrently
            if (tid >= 64 && tid < 96) Zb[(bi + 1) % 3][tid & 31] = 0.f;
            __syncthreads();  // the ONE barrier per bi
            c = ex * __builtin_amdgcn_rcpf(Zb[bi % 3][r]);
        } else {
            c = c0;  // no barrier, no DS in round-0 loop
        }

        const int q4 = (bi & 3) * 8;
#pragma unroll
        for (int k = 0; k < 8; ++k) s_acc[q4 + k] = fmaf(c, hat[k], s_acc[q4 + k]);

        if ((bi & 3) == 3) {
            // splitting butterfly: 32 values (4 bi x 8 k) over 32 r-lanes,
            // final: lane r holds total for idx=r (bi_local=r>>3, k=r&7)
#pragma unroll
            for (int dist = 16; dist >= 1; dist >>= 1) {
                const bool hi = (r & dist) != 0;
#pragma unroll
                for (int m = 0; m < dist; ++m) {
                    float mine = hi ? s_acc[m + dist] : s_acc[m];
                    float send = hi ? s_acc[m] : s_acc[m + dist];
                    s_acc[m] = mine + __shfl_xor(send, dist);
                }
            }
            const int b_out = bg * BT + (bi & 4) + (r >> 3);
            atomicAdd(&s_out[(size_t)b_out * SOUT + j * DV + h * 8 + (r & 7)], s_acc[0]);
#pragma unroll
            for (int k = 0; k < 32; ++k) s_acc[k] = 0.f;
        }
    }
}

__global__ __launch_bounds__(192) void squash_kernel(const float* __restrict__ s_ws,
                                                     float* __restrict__ vout) {
    const int b = blockIdx.x, t = threadIdx.x;
    if (t < SOUT) {
        float sv = s_ws[(size_t)b * SOUT + t];
        float s2 = sv * sv;
#pragma unroll
        for (int mk = 8; mk >= 1; mk >>= 1) s2 += __shfl_xor(s2, mk, 16);
        float scale = sqrtf(s2) / (1.f + s2);
        vout[(size_t)b * SOUT + t] = scale * sv;
    }
}

extern "C" void kernel_launch(void* const* d_in, const int* in_sizes, int n_in,
                              void* d_out, int out_size, void* d_ws, size_t ws_size,
                              hipStream_t stream) {
    const float* X = (const float*)d_in[0];     // [256,1152,8]
    const float* W = (const float*)d_in[1];     // [1152,10,8,16]
    const float* bias = (const float*)d_in[2];  // [1,1152,10]
    float* out = (float*)d_out;

    // ws (floats): Wc (NW/2) | s0 | s1 | s2   = ~3.4 MB
    float* base = (float*)d_ws;
    int4* Wc = (int4*)d_ws;
    float* s0 = base + NW / 2;
    float* s1 = s0 + SB;
    float* s2 = s1 + SB;

    wprep_kernel<<<dim3(720), dim3(256), 0, stream>>>(W, Wc);
    zero_kernel<<<dim3(120), dim3(256), 0, stream>>>((float4*)s0);  // s0,s1,s2

    dim3 rg(NGP, NBG);  // (36, 32)
    round_kernel<0><<<rg, TPB, 0, stream>>>(X, Wc, bias, nullptr, nullptr, s0);
    round_kernel<1><<<rg, TPB, 0, stream>>>(X, Wc, bias, s0, nullptr, s1);   // v1 fused
    round_kernel<2><<<rg, TPB, 0, stream>>>(X, Wc, bias, s0, s1, s2);        // v1+v2 fused
    squash_kernel<<<NB, 192, 0, stream>>>(s2, out);
}